// Round 4
// baseline (435.271 us; speedup 1.0000x reference)
//
#include <hip/hip_runtime.h>

#define TPB 256
#define SPB 9          // samples per block
#define XSTRIDE 1396   // uints per sample x region (swizzled planes, max 1368+25)
#define HSTRIDE 700    // uints per sample h1 region (50 planes x 14)

__device__ __forceinline__ unsigned bf16rne(float f) {
    unsigned u = __float_as_uint(f);
    return (u + 0x7fffu + ((u >> 16) & 1u)) >> 16;
}
__device__ __forceinline__ void unpack2(unsigned u, float& a, float& b) {
    a = __uint_as_float(u << 16);
    b = __uint_as_float(u & 0xffff0000u);
}
// swizzled x-plane base (uints): kills the 28p mod-32 bank aliasing for plane deltas of 8
__device__ __forceinline__ int xplane(int p) {
    return 28 * p + (((p >> 3) & 7) << 2);
}

__global__ __launch_bounds__(TPB, 2)
void conv4d_fused(const float* __restrict__ x,
                  const float* __restrict__ w1, const float* __restrict__ b1,
                  const float* __restrict__ w2, const float* __restrict__ b2,
                  float* __restrict__ out, int B)
{
    __shared__ __align__(16) unsigned s_xu[SPB * XSTRIDE];   // 50256 B
    __shared__ __align__(16) unsigned s_h1[SPB * HSTRIDE];   // 25200 B
    __shared__ __align__(16) float s_w1[9 * 2 * 12];         // [klkd][o][12]    864 B
    __shared__ __align__(16) float s_w2[2 * 9 * 4 * 12];     // [c][klkd][o2][12] 3456 B

    const int t  = threadIdx.x;
    const int s0 = blockIdx.x * SPB;

    // ---- weights -> LDS (fp32, layout for broadcast float4 reads)
    for (int i = t; i < 162; i += TPB) {
        int o = i / 81, r = i - o * 81;
        int klkd = r / 9, tap = r - klkd * 9;
        s_w1[(klkd * 2 + o) * 12 + tap] = w1[i];
    }
    for (int i = t; i < 648; i += TPB) {
        int o2 = i / 162, r = i - o2 * 162;
        int c = r / 81, r2 = r - c * 81;
        int klkd = r2 / 9, tap = r2 - klkd * 9;
        s_w2[((c * 9 + klkd) * 4 + o2) * 12 + tap] = w2[i];
    }

    // ---- x staging: fp32 global -> packed bf16 LDS, swizzled plane bases
    for (int s = 0; s < SPB; ++s) {
        if (s0 + s >= B) break;
        const float* gx = x + (size_t)(s0 + s) * 2401;
        unsigned* xw = s_xu + s * XSTRIDE;
        for (int i = t; i < 1225; i += TPB) {
            int p = i / 25;              // plane 0..48
            int j = i - p * 25;          // pair-unit 0..24
            const float* gp = gx + p * 49 + 2 * j;
            float a = gp[0];
            float b = (j < 24) ? gp[1] : 0.0f;
            xw[xplane(p) + j] = bf16rne(a) | (bf16rne(b) << 16);
        }
    }
    __syncthreads();

    // ---- conv1 + ReLU: task = (s, l, d), BOTH output channels. 225 tasks.
    if (t < SPB * 25) {
        int s  = t / 25;
        int ld = t - s * 25;
        if (s0 + s < B) {
            int l = ld / 5, d = ld - (ld / 5) * 5;
            float acc0[25], acc1[25];
            const float bb0 = b1[0], bb1 = b1[1];
            #pragma unroll
            for (int i = 0; i < 25; ++i) { acc0[i] = bb0; acc1[i] = bb1; }

            const unsigned* xw = s_xu + s * XSTRIDE;
            const int pbase = l * 7 + d;
            #pragma unroll
            for (int kl = 0; kl < 3; ++kl)
            #pragma unroll
            for (int kd = 0; kd < 3; ++kd) {
                const int p = pbase + kl * 7 + kd;
                const unsigned* pp = xw + xplane(p);
                unsigned u[25];
                #pragma unroll
                for (int k = 0; k < 6; ++k) {
                    uint4 q = ((const uint4*)pp)[k];
                    u[4*k] = q.x; u[4*k+1] = q.y; u[4*k+2] = q.z; u[4*k+3] = q.w;
                }
                u[24] = pp[24];
                float X[50];
                #pragma unroll
                for (int k = 0; k < 25; ++k) unpack2(u[k], X[2*k], X[2*k+1]);

                const float* wp = s_w1 + (kl * 3 + kd) * 24;   // broadcast
                float wv0[9], wv1[9];
                {
                    float4 A = *(const float4*)wp;
                    float4 Bq = *(const float4*)(wp + 4);
                    wv0[0]=A.x; wv0[1]=A.y; wv0[2]=A.z; wv0[3]=A.w;
                    wv0[4]=Bq.x; wv0[5]=Bq.y; wv0[6]=Bq.z; wv0[7]=Bq.w;
                    wv0[8]=wp[8];
                    float4 C = *(const float4*)(wp + 12);
                    float4 Dq = *(const float4*)(wp + 16);
                    wv1[0]=C.x; wv1[1]=C.y; wv1[2]=C.z; wv1[3]=C.w;
                    wv1[4]=Dq.x; wv1[5]=Dq.y; wv1[6]=Dq.z; wv1[7]=Dq.w;
                    wv1[8]=wp[20];
                }

                #pragma unroll
                for (int kh = 0; kh < 3; ++kh)
                #pragma unroll
                for (int kw = 0; kw < 3; ++kw) {
                    const float w0v = wv0[kh*3+kw], w1v = wv1[kh*3+kw];
                    #pragma unroll
                    for (int h = 0; h < 5; ++h)
                    #pragma unroll
                    for (int w = 0; w < 5; ++w) {
                        const float xv = X[(h+kh)*7 + (w+kw)];
                        acc0[h*5+w] += xv * w0v;
                        acc1[h*5+w] += xv * w1v;
                    }
                }
            }

            // ReLU + pack + store both h1 planes (13 uints @ stride-14 planes)
            unsigned* hp0 = s_h1 + s * HSTRIDE + 14 * ld;
            unsigned* hp1 = hp0 + 14 * 25;
            unsigned pk[13];
            #pragma unroll
            for (int k = 0; k < 12; ++k)
                pk[k] = bf16rne(fmaxf(acc0[2*k],0.f)) | (bf16rne(fmaxf(acc0[2*k+1],0.f)) << 16);
            pk[12] = bf16rne(fmaxf(acc0[24],0.f));
            #pragma unroll
            for (int k = 0; k < 6; ++k) ((uint2*)hp0)[k] = make_uint2(pk[2*k], pk[2*k+1]);
            hp0[12] = pk[12];
            #pragma unroll
            for (int k = 0; k < 12; ++k)
                pk[k] = bf16rne(fmaxf(acc1[2*k],0.f)) | (bf16rne(fmaxf(acc1[2*k+1],0.f)) << 16);
            pk[12] = bf16rne(fmaxf(acc1[24],0.f));
            #pragma unroll
            for (int k = 0; k < 6; ++k) ((uint2*)hp1)[k] = make_uint2(pk[2*k], pk[2*k+1]);
            hp1[12] = pk[12];
        }
    }
    __syncthreads();

    // ---- conv2 + ReLU: task = (s, l, d), ALL 4 output channels. 81 tasks.
    if (t < SPB * 9) {
        int s  = t / 9;
        int ld = t - s * 9;
        if (s0 + s < B) {
            int l = ld / 3, d = ld - (ld / 3) * 3;
            float acc[4][9];
            #pragma unroll
            for (int o2 = 0; o2 < 4; ++o2) {
                const float bb = b2[o2];
                #pragma unroll
                for (int i = 0; i < 9; ++i) acc[o2][i] = bb;
            }

            const unsigned* hw = s_h1 + s * HSTRIDE;
            const int qbase = l * 5 + d;
            #pragma unroll
            for (int c = 0; c < 2; ++c)
            #pragma unroll
            for (int kl = 0; kl < 3; ++kl)
            #pragma unroll
            for (int kd = 0; kd < 3; ++kd) {
                const int q = c * 25 + qbase + kl * 5 + kd;
                const unsigned* pp = hw + 14 * q;
                unsigned u[13];
                #pragma unroll
                for (int k = 0; k < 6; ++k) {
                    uint2 qq = ((const uint2*)pp)[k];
                    u[2*k] = qq.x; u[2*k+1] = qq.y;
                }
                u[12] = pp[12];
                float X[26];
                #pragma unroll
                for (int k = 0; k < 13; ++k) unpack2(u[k], X[2*k], X[2*k+1]);

                const float* wp = s_w2 + (c * 9 + (kl*3+kd)) * 48;   // broadcast
                float wv[4][9];
                #pragma unroll
                for (int o2 = 0; o2 < 4; ++o2) {
                    const float* wq = wp + o2 * 12;
                    float4 A = *(const float4*)wq;
                    float4 Bq = *(const float4*)(wq + 4);
                    wv[o2][0]=A.x; wv[o2][1]=A.y; wv[o2][2]=A.z; wv[o2][3]=A.w;
                    wv[o2][4]=Bq.x; wv[o2][5]=Bq.y; wv[o2][6]=Bq.z; wv[o2][7]=Bq.w;
                    wv[o2][8]=wq[8];
                }

                #pragma unroll
                for (int kh = 0; kh < 3; ++kh)
                #pragma unroll
                for (int kw = 0; kw < 3; ++kw) {
                    const float w0v = wv[0][kh*3+kw], w1v = wv[1][kh*3+kw];
                    const float w2v = wv[2][kh*3+kw], w3v = wv[3][kh*3+kw];
                    #pragma unroll
                    for (int h = 0; h < 3; ++h)
                    #pragma unroll
                    for (int w = 0; w < 3; ++w) {
                        const float xv = X[(h+kh)*5 + (w+kw)];
                        acc[0][h*3+w] += xv * w0v;
                        acc[1][h*3+w] += xv * w1v;
                        acc[2][h*3+w] += xv * w2v;
                        acc[3][h*3+w] += xv * w3v;
                    }
                }
            }

            float* op = out + (size_t)(s0 + s) * 324 + ld * 9;
            #pragma unroll
            for (int o2 = 0; o2 < 4; ++o2)
                #pragma unroll
                for (int i = 0; i < 9; ++i)
                    op[o2 * 81 + i] = fmaxf(acc[o2][i], 0.f);
        }
    }
}

extern "C" void kernel_launch(void* const* d_in, const int* in_sizes, int n_in,
                              void* d_out, int out_size, void* d_ws, size_t ws_size,
                              hipStream_t stream)
{
    const float* x  = (const float*)d_in[0];
    const float* w1 = (const float*)d_in[1];
    const float* b1 = (const float*)d_in[2];
    const float* w2 = (const float*)d_in[3];
    const float* b2 = (const float*)d_in[4];
    float* out = (float*)d_out;

    const int B = in_sizes[0] / 2401;          // 16384
    const int grid = (B + SPB - 1) / SPB;      // 1821 blocks
    conv4d_fused<<<grid, TPB, 0, stream>>>(x, w1, b1, w2, b2, out, B);
}

// Round 6
// 369.815 us; speedup vs baseline: 1.1770x; 1.1770x over previous
//
#include <hip/hip_runtime.h>
#include <hip/hip_fp16.h>

#define TPB 256
#define SPB 9          // samples per block
#define XS  1372       // uints per sample: 49 planes * 28 (7 rows * 4 even-pair uints)
#define HS  700        // uints per sample: 25 planes * 28 (25 c-pair uints + 3 pad)

__device__ __forceinline__ unsigned h2u(__half2 h) { return __builtin_bit_cast(unsigned, h); }
__device__ __forceinline__ __half2 u2h(unsigned u) { return __builtin_bit_cast(__half2, u); }
__device__ __forceinline__ unsigned pkf(float a, float b) { return h2u(__floats2half2_rn(a, b)); }
// packed fp16 ReLU: v_pk_max_f16 with inline-constant 0
__device__ __forceinline__ unsigned pkrelu(unsigned u) {
    unsigned r;
    __asm__ volatile("v_pk_max_f16 %0, %1, 0" : "=v"(r) : "v"(u));
    return r;
}

__global__ __launch_bounds__(TPB, 2)
void conv4d_fused(const float* __restrict__ x,
                  const float* __restrict__ w1, const float* __restrict__ b1,
                  const float* __restrict__ w2, const float* __restrict__ b2,
                  float* __restrict__ out, int B)
{
    __shared__ __align__(16) unsigned s_x[SPB * XS];    // 49392 B
    __shared__ __align__(16) unsigned s_h[SPB * HS];    // 25200 B
    __shared__ __align__(16) unsigned s_w1d[216];       // [klkd][o][9 dup-pairs +3 pad]
    __shared__ __align__(16) unsigned s_w2d[432];       // [klkd][o2][9 c-pairs +3 pad]
    __shared__ unsigned s_b1d[2];
    __shared__ float s_b2[4];

    const int t  = threadIdx.x;
    const int s0 = blockIdx.x * SPB;
    const int ns = min(SPB, B - s0);

    // ---- stage weights: w1 as duplicated fp16 pairs, w2 as channel fp16 pairs
    for (int i = t; i < 162; i += TPB) {
        int o = i / 81, r81 = i - 81 * o;
        int klkd = r81 / 9, t9 = r81 - 9 * klkd;
        float v = w1[i];
        s_w1d[((klkd * 2 + o) * 12) + t9] = pkf(v, v);
    }
    for (int i = t; i < 324; i += TPB) {
        int o2 = i / 81, r81 = i - 81 * o2;
        int klkd = r81 / 9, t9 = r81 - 9 * klkd;
        s_w2d[((klkd * 4 + o2) * 12) + t9] = pkf(w2[o2 * 162 + r81], w2[o2 * 162 + 81 + r81]);
    }
    if (t < 2) { float v = b1[t]; s_b1d[t] = pkf(v, v); }
    if (t < 4) s_b2[t] = b2[t];

    // ---- stage x: fp32 -> even-phase fp16 pairs; LDS index == unit index (linear)
    {
        const int nunit = ns * XS;
        for (int v = t; v < nunit; v += TPB) {
            int s  = v / XS;     int r0 = v - s * XS;
            int p  = r0 / 28;    int r1 = r0 - p * 28;
            int r  = r1 >> 2, c = r1 & 3;
            const float* gp = x + (size_t)(s0 + s) * 2401 + p * 49 + r * 7;
            float a = gp[c < 3 ? 2 * c : 6];
            float b = (c < 3) ? gp[2 * c + 1] : 0.0f;
            s_x[v] = pkf(a, b);
        }
    }
    __syncthreads();

    // ---- conv1 (pk_fma over W-position pairs), both channels. 225 tasks.
    if (t < SPB * 25) {
        int s = t / 25, ld = t - 25 * s;
        if (s < ns) {
            int l = ld / 5, d = ld - 5 * l;
            __half2 acc[2][5][3];
            {
                __half2 bb0 = u2h(s_b1d[0]), bb1 = u2h(s_b1d[1]);
                #pragma unroll
                for (int h = 0; h < 5; ++h)
                    #pragma unroll
                    for (int j = 0; j < 3; ++j) { acc[0][h][j] = bb0; acc[1][h][j] = bb1; }
            }
            const unsigned* xb = s_x + s * XS + (l * 7 + d) * 28;

            #pragma unroll
            for (int kl = 0; kl < 3; ++kl)
            #pragma unroll
            for (int kd = 0; kd < 3; ++kd) {
                const unsigned* pp = xb + (kl * 7 + kd) * 28;
                unsigned e[7][4];
                #pragma unroll
                for (int r = 0; r < 7; ++r) {
                    uint4 q = ((const uint4*)pp)[r];
                    e[r][0] = q.x; e[r][1] = q.y; e[r][2] = q.z; e[r][3] = q.w;
                }
                unsigned od[7][3];
                #pragma unroll
                for (int r = 0; r < 7; ++r)
                    #pragma unroll
                    for (int j = 0; j < 3; ++j)
                        od[r][j] = __builtin_amdgcn_alignbit(e[r][j + 1], e[r][j], 16);

                unsigned wv[2][9];
                #pragma unroll
                for (int o = 0; o < 2; ++o) {
                    const unsigned* wb = s_w1d + ((kl * 3 + kd) * 2 + o) * 12;
                    uint4 qa = ((const uint4*)wb)[0];
                    uint4 qb = ((const uint4*)wb)[1];
                    wv[o][0] = qa.x; wv[o][1] = qa.y; wv[o][2] = qa.z; wv[o][3] = qa.w;
                    wv[o][4] = qb.x; wv[o][5] = qb.y; wv[o][6] = qb.z; wv[o][7] = qb.w;
                    wv[o][8] = wb[8];
                }

                #pragma unroll
                for (int kh = 0; kh < 3; ++kh)
                #pragma unroll
                for (int h = 0; h < 5; ++h) {
                    const int row = h + kh;
                    #pragma unroll
                    for (int kw = 0; kw < 3; ++kw) {
                        // X2 for acc col j (positions 2j, 2j+1) shifted by kw
                        #pragma unroll
                        for (int j = 0; j < 3; ++j) {
                            unsigned xu = (kw == 0) ? e[row][j]
                                        : (kw == 1) ? od[row][j]
                                                    : e[row][j + 1];
                            __half2 X2 = u2h(xu);
                            acc[0][h][j] = __hfma2(X2, u2h(wv[0][kh * 3 + kw]), acc[0][h][j]);
                            acc[1][h][j] = __hfma2(X2, u2h(wv[1][kh * 3 + kw]), acc[1][h][j]);
                        }
                    }
                }
            }

            // ReLU + repack (pos-pairs -> channel-pairs) + store h1 plane
            unsigned* hp = s_h + s * HS + ld * 28;
            unsigned o25[25];
            #pragma unroll
            for (int h = 0; h < 5; ++h) {
                unsigned c0[3], c1[3];
                #pragma unroll
                for (int j = 0; j < 3; ++j) {
                    c0[j] = pkrelu(h2u(acc[0][h][j]));
                    c1[j] = pkrelu(h2u(acc[1][h][j]));
                }
                o25[h * 5 + 0] = __builtin_amdgcn_perm(c1[0], c0[0], 0x05040100u);
                o25[h * 5 + 1] = __builtin_amdgcn_perm(c1[0], c0[0], 0x07060302u);
                o25[h * 5 + 2] = __builtin_amdgcn_perm(c1[1], c0[1], 0x05040100u);
                o25[h * 5 + 3] = __builtin_amdgcn_perm(c1[1], c0[1], 0x07060302u);
                o25[h * 5 + 4] = __builtin_amdgcn_perm(c1[2], c0[2], 0x05040100u);
            }
            #pragma unroll
            for (int k = 0; k < 6; ++k)
                ((uint4*)hp)[k] = make_uint4(o25[4 * k], o25[4 * k + 1], o25[4 * k + 2], o25[4 * k + 3]);
            hp[24] = o25[24];
        }
    }
    __syncthreads();

    // ---- conv2 (pk_fma over channel pairs), 2 output channels per task. 162 tasks.
    if (t < SPB * 18) {
        int q = t >> 1, o2p = t & 1;
        int s = q / 9, ld = q - 9 * s;
        if (s < ns) {
            int l = ld / 3, d = ld - 3 * l;
            __half2 acc[2][9];
            #pragma unroll
            for (int j = 0; j < 2; ++j)
                #pragma unroll
                for (int i = 0; i < 9; ++i) acc[j][i] = u2h(0u);

            const unsigned* hb = s_h + s * HS + (l * 5 + d) * 28;
            #pragma unroll
            for (int kl = 0; kl < 3; ++kl)
            #pragma unroll
            for (int kd = 0; kd < 3; ++kd) {
                const unsigned* pp = hb + (kl * 5 + kd) * 28;
                unsigned u[25];
                #pragma unroll
                for (int k = 0; k < 6; ++k) {
                    uint4 qq = ((const uint4*)pp)[k];
                    u[4*k] = qq.x; u[4*k+1] = qq.y; u[4*k+2] = qq.z; u[4*k+3] = qq.w;
                }
                u[24] = pp[24];

                #pragma unroll
                for (int j = 0; j < 2; ++j) {
                    const int o2 = 2 * o2p + j;
                    const unsigned* wb = s_w2d + ((kl * 3 + kd) * 4 + o2) * 12;
                    uint4 qa = ((const uint4*)wb)[0];
                    uint4 qb = ((const uint4*)wb)[1];
                    unsigned wv[9] = {qa.x, qa.y, qa.z, qa.w, qb.x, qb.y, qb.z, qb.w, wb[8]};
                    #pragma unroll
                    for (int kh = 0; kh < 3; ++kh)
                    #pragma unroll
                    for (int kw = 0; kw < 3; ++kw) {
                        __half2 W2 = u2h(wv[kh * 3 + kw]);
                        #pragma unroll
                        for (int h = 0; h < 3; ++h)
                        #pragma unroll
                        for (int w = 0; w < 3; ++w)
                            acc[j][h * 3 + w] =
                                __hfma2(u2h(u[(h + kh) * 5 + (w + kw)]), W2, acc[j][h * 3 + w]);
                    }
                }
            }

            float* op = out + (size_t)(s0 + s) * 324 + o2p * 162 + ld * 9;
            #pragma unroll
            for (int j = 0; j < 2; ++j) {
                const float bb = s_b2[2 * o2p + j];
                #pragma unroll
                for (int i = 0; i < 9; ++i) {
                    float v = __low2float(acc[j][i]) + __high2float(acc[j][i]) + bb;
                    op[j * 81 + i] = fmaxf(v, 0.0f);
                }
            }
        }
    }
}

extern "C" void kernel_launch(void* const* d_in, const int* in_sizes, int n_in,
                              void* d_out, int out_size, void* d_ws, size_t ws_size,
                              hipStream_t stream)
{
    const float* x  = (const float*)d_in[0];
    const float* w1 = (const float*)d_in[1];
    const float* b1 = (const float*)d_in[2];
    const float* w2 = (const float*)d_in[3];
    const float* b2 = (const float*)d_in[4];
    float* out = (float*)d_out;

    const int B = in_sizes[0] / 2401;          // 16384
    const int grid = (B + SPB - 1) / SPB;      // 1821 blocks
    conv4d_fused<<<grid, TPB, 0, stream>>>(x, w1, b1, w2, b2, out, B);
}